// Round 9
// baseline (1405.696 us; speedup 1.0000x reference)
//
#include <hip/hip_runtime.h>
#include <hip/hip_fp16.h>

#define N_JOB 500000
#define N_WORKER 50000
#define E_PRE 4000000
#define E_NXT 4000000
#define E_PROC 2000000

// dst/src-window partition: 62 windows x 8192 nodes
#define WBITS 13
#define WSZ 8192
#define NWIN 62                    // ceil(500000/8192)
#define CAP_JJ 67584               // mean 65536 + 8 sigma (sigma ~254)
#define CAP_PR 34000               // mean 32768 + 6.8 sigma
#define CAP_SR 67584

#define EPB 8192                   // edges per partition block
#define NB_PRE ((E_PRE + EPB - 1) / EPB)     // 489
#define NB_PROC ((E_PROC + EPB - 1) / EPB)   // 245

// gcur layout: [0,62) rel0-dst | [62,124) rel1-dst | [124,186) proc-dst
//              [186,248) rel0-src | [248,310) rel1-src
__global__ void cursor_init(int* __restrict__ gcur) {
    int t = threadIdx.x;
    if (t < 2 * NWIN) gcur[t] = t * CAP_JJ;
    else if (t < 3 * NWIN) gcur[t] = (t - 2 * NWIN) * CAP_PR;
    else if (t < 5 * NWIN) gcur[t] = (t - 3 * NWIN) * CAP_SR;
}

// ---------------------------------------------------------------------------
// Partition: each block owns 8192 edges of one relation. LDS histogram by
// window -> one global cursor reservation per (block,segment) -> replay
// writing packed bucket entries with plain stores.
// jj entry: (dst&8191)<<19|src. proc: ((dl<<16)|src, eid). src entry: u16.
// ---------------------------------------------------------------------------
__global__ __launch_bounds__(256) void partition_kernel(
        const int* __restrict__ pre_src, const int* __restrict__ pre_dst,
        const int* __restrict__ nxt_src, const int* __restrict__ nxt_dst,
        const int* __restrict__ proc_src, const int* __restrict__ proc_dst,
        int* __restrict__ gcur, unsigned* __restrict__ jjb,
        int2* __restrict__ procb, unsigned short* __restrict__ srcb) {
    __shared__ int cntD[NWIN], cntS[NWIN], basD[NWIN], basS[NWIN];
    __shared__ int curD[NWIN], curS[NWIN];
    int t = threadIdx.x;
    int b = blockIdx.x;
    int rel, lo, hi;
    const int *dstp, *srcp;
    if (b < NB_PRE) {
        rel = 0; dstp = pre_dst; srcp = pre_src;
        lo = b * EPB; hi = min(lo + EPB, E_PRE);
    } else if (b < 2 * NB_PRE) {
        rel = 1; b -= NB_PRE; dstp = nxt_dst; srcp = nxt_src;
        lo = b * EPB; hi = min(lo + EPB, E_NXT);
    } else {
        rel = 2; b -= 2 * NB_PRE; dstp = proc_dst; srcp = proc_src;
        lo = b * EPB; hi = min(lo + EPB, E_PROC);
    }
    if (t < NWIN) { cntD[t] = 0; cntS[t] = 0; }
    __syncthreads();
    if (rel < 2) {
        for (int i = lo + t; i < hi; i += 256) {
            atomicAdd(&cntD[dstp[i] >> WBITS], 1);
            atomicAdd(&cntS[srcp[i] >> WBITS], 1);
        }
        __syncthreads();
        if (t < NWIN) {
            int c = cntD[t];
            basD[t] = c ? atomicAdd(&gcur[rel * NWIN + t], c) : 0;
            c = cntS[t];
            basS[t] = c ? atomicAdd(&gcur[3 * NWIN + rel * NWIN + t], c) : 0;
            curD[t] = 0; curS[t] = 0;
        }
        __syncthreads();
        for (int i = lo + t; i < hi; i += 256) {
            int d = dstp[i], s = srcp[i];
            int wd = d >> WBITS, wsw = s >> WBITS;
            int pD = basD[wd] + atomicAdd(&curD[wd], 1);
            jjb[pD] = ((unsigned)(d & (WSZ - 1)) << 19) | (unsigned)s;
            int pS = basS[wsw] + atomicAdd(&curS[wsw], 1);
            srcb[pS] = (unsigned short)(s & (WSZ - 1));
        }
    } else {
        for (int i = lo + t; i < hi; i += 256)
            atomicAdd(&cntD[dstp[i] >> WBITS], 1);
        __syncthreads();
        if (t < NWIN) {
            int c = cntD[t];
            basD[t] = c ? atomicAdd(&gcur[2 * NWIN + t], c) : 0;
            curD[t] = 0;
        }
        __syncthreads();
        for (int i = lo + t; i < hi; i += 256) {
            int d = dstp[i], s = srcp[i];
            int wd = d >> WBITS;
            int pD = basD[wd] + atomicAdd(&curD[wd], 1);
            procb[pD] = make_int2(((d & (WSZ - 1)) << 16) | s, i);
        }
    }
}

// ---------------------------------------------------------------------------
// csr_build: one block per (rel,window). Fuses count + scan + place with LDS
// only; writes row ENDS + scatters into own contiguous adj region.
// For jj relations the scatter runs as 8 filtered sub-passes over the
// (L2-resident) bucket segment so each row's neighbor list is ordered by
// src-OCTANT (65536 nodes = 2MB of fp16 h): gather threads walking rows
// left->right then hit a shared, L2-fitting h window at any instant.
// ---------------------------------------------------------------------------
__global__ __launch_bounds__(256) void csr_build(
        const unsigned* __restrict__ jjb, const int2* __restrict__ procb,
        const int* __restrict__ gcur, int* __restrict__ off,
        int* __restrict__ adj_jj, int2* __restrict__ adj_proc) {
    __shared__ int hist[WSZ];
    __shared__ int scanB[WSZ];
    __shared__ int part[256];
    __shared__ int wcnt[NWIN];
    __shared__ int baseS;
    int t = threadIdx.x;
    int rel = blockIdx.x / NWIN;
    int w = blockIdx.x % NWIN;
    int segbase, segend;
    if (rel < 2) { int k = rel * NWIN + w; segbase = k * CAP_JJ; segend = gcur[k]; }
    else         { segbase = w * CAP_PR; segend = gcur[2 * NWIN + w]; }
    if (t < NWIN) {
        if (rel < 2) wcnt[t] = gcur[rel * NWIN + t] - (rel * NWIN + t) * CAP_JJ;
        else         wcnt[t] = gcur[2 * NWIN + t] - t * CAP_PR;
    }
    for (int i = t; i < WSZ; i += 256) hist[i] = 0;
    __syncthreads();
    if (t == 0) {
        int bb = (rel == 1) ? E_PRE : 0;
        for (int i = 0; i < w; ++i) bb += wcnt[i];
        baseS = bb;
    }
    if (rel < 2) {
        for (int p = segbase + t; p < segend; p += 256)
            atomicAdd(&hist[jjb[p] >> 19], 1);
    } else {
        for (int p = segbase + t; p < segend; p += 256)
            atomicAdd(&hist[procb[p].x >> 16], 1);
    }
    __syncthreads();
    {
        int mb = t * 32;
        int sum = 0;
        for (int j = 0; j < 32; ++j) { int v = hist[mb + j]; scanB[mb + j] = sum; sum += v; }
        part[t] = sum;
        __syncthreads();
        if (t == 0) { int r = 0; for (int i = 0; i < 256; ++i) { int v = part[i]; part[i] = r; r += v; } }
        __syncthreads();
        int add = part[t] + baseS;
        for (int j = 0; j < 32; ++j) scanB[mb + j] += add;
    }
    __syncthreads();
    int nlo = w * WSZ;
    int nloc = min(WSZ, N_JOB - nlo);
    for (int i = t; i < nloc; i += 256)
        off[rel * N_JOB + nlo + i] = scanB[i] + hist[i];   // row ENDS
    __syncthreads();
    if (rel < 2) {
        // 8 sub-passes: scatter only edges whose src octant == oct, barrier
        // between passes -> each row ends up sorted by src octant.
        for (int oct = 0; oct < 8; ++oct) {
            for (int p = segbase + t; p < segend; p += 256) {
                unsigned e = jjb[p];
                if ((int)((e >> 16) & 7u) == oct) {     // bits 16..18 of src
                    int slot = atomicAdd(&scanB[e >> 19], 1);
                    adj_jj[slot] = (int)(e & 0x7FFFFu);
                }
            }
            __syncthreads();
        }
    } else {
        for (int p = segbase + t; p < segend; p += 256) {
            int2 e = procb[p];
            int slot = atomicAdd(&scanB[e.x >> 16], 1);
            adj_proc[slot] = make_int2(e.x & 0xFFFF, e.y);
        }
    }
}

// ---------------------------------------------------------------------------
// outdeg_build: one block per (rel,window); LDS histogram of u16 src-locals,
// writes rsqrt(max(deg,1)) floats directly.
// ---------------------------------------------------------------------------
__global__ __launch_bounds__(256) void outdeg_build(
        const unsigned short* __restrict__ srcb, const int* __restrict__ gcur,
        float* __restrict__ sc_pre, float* __restrict__ sc_nxt) {
    __shared__ int hist[WSZ];
    int t = threadIdx.x;
    int rel = blockIdx.x / NWIN;
    int w = blockIdx.x % NWIN;
    int k = rel * NWIN + w;
    int segbase = k * CAP_SR;
    int segend = gcur[3 * NWIN + k];
    for (int i = t; i < WSZ; i += 256) hist[i] = 0;
    __syncthreads();
    int cnt = segend - segbase;
    const unsigned* p2 = (const unsigned*)(srcb + segbase);
    int n2 = cnt >> 1;
    for (int i = t; i < n2; i += 256) {
        unsigned v = p2[i];
        atomicAdd(&hist[v & 0xFFFFu], 1);
        atomicAdd(&hist[v >> 16], 1);
    }
    if (t == 0 && (cnt & 1)) atomicAdd(&hist[srcb[segend - 1]], 1);
    __syncthreads();
    float* scp = rel ? sc_nxt : sc_pre;
    int nlo = w * WSZ;
    int nloc = min(WSZ, N_JOB - nlo);
    for (int i = t; i < nloc; i += 256) {
        int d = hist[i];
        scp[nlo + i] = rsqrtf((float)(d < 1 ? 1 : d));
    }
}

__device__ __forceinline__ unsigned pack_h2(float a, float b) {
    __half2 h = __float22half2_rn(make_float2(a, b));
    return *reinterpret_cast<unsigned*>(&h);
}
__device__ __forceinline__ float2 unpack_h2(unsigned u) {
    __half2 h = *reinterpret_cast<__half2*>(&u);
    return __half22float2(h);
}

// ---------------------------------------------------------------------------
// Embedding. HOUT=true: write fp16 row (16 halfs). HOUT=false: f32 row (hw).
// ---------------------------------------------------------------------------
template <int F, bool HOUT>
__global__ void embed_kernel(const float* __restrict__ feat, const float* __restrict__ W,
                             const float* __restrict__ b, void* __restrict__ outp, int n) {
    __shared__ float Ws[F * 16];
    __shared__ float bs[16];
    int t = threadIdx.x;
    if (t < F * 16) Ws[t] = W[t];
    if (t < 16) bs[t] = b[t];
    __syncthreads();
    int i = blockIdx.x * blockDim.x + t;
    if (i >= n) return;
    float f[F];
#pragma unroll
    for (int k = 0; k < F; k++) f[k] = feat[(size_t)i * F + k];
    float o[16];
#pragma unroll
    for (int d = 0; d < 16; d++) {
        float s = bs[d];
#pragma unroll
        for (int k = 0; k < F; k++) s += f[k] * Ws[k * 16 + d];
        o[d] = s;
    }
    if (HOUT) {
        uint4* dst = (uint4*)((__half*)outp + (size_t)i * 16);
        dst[0] = make_uint4(pack_h2(o[0], o[1]), pack_h2(o[2], o[3]),
                            pack_h2(o[4], o[5]), pack_h2(o[6], o[7]));
        dst[1] = make_uint4(pack_h2(o[8], o[9]), pack_h2(o[10], o[11]),
                            pack_h2(o[12], o[13]), pack_h2(o[14], o[15]));
    } else {
        float4* dst4 = (float4*)((float*)outp + (size_t)i * 16);
        dst4[0] = make_float4(o[0], o[1], o[2], o[3]);
        dst4[1] = make_float4(o[4], o[5], o[6], o[7]);
        dst4[2] = make_float4(o[8], o[9], o[10], o[11]);
        dst4[3] = make_float4(o[12], o[13], o[14], o[15]);
    }
}

// ---------------------------------------------------------------------------
// Merged per-layer gather with fp16 node features: pre + nxt + sage + self.
// 4 lanes per node; lane c owns elements [4c,4c+4). Rows are src-octant
// sorted, so concurrent threads' h-gathers concentrate in a 2MB window that
// fits each XCD's L2. Accumulation/weights f32. FINAL writes scores only.
// ---------------------------------------------------------------------------
__device__ __forceinline__ void mm_accum(const float* __restrict__ Ws, float4 a, int c, float o[4]) {
#pragma unroll
    for (int g = 0; g < 4; ++g) {
        float a0 = __shfl(a.x, g, 4);
        float a1 = __shfl(a.y, g, 4);
        float a2 = __shfl(a.z, g, 4);
        float a3 = __shfl(a.w, g, 4);
        const float* wr = &Ws[(4 * g) * 16 + c * 4];
#pragma unroll
        for (int j = 0; j < 4; ++j)
            o[j] += a0 * wr[j] + a1 * wr[16 + j] + a2 * wr[32 + j] + a3 * wr[48 + j];
    }
}

__device__ __forceinline__ float4 load_h16(const __half* __restrict__ h16, int row, int c) {
    uint2 raw = *(const uint2*)(h16 + (size_t)row * 16 + c * 4);
    float2 lo = unpack_h2(raw.x), hi = unpack_h2(raw.y);
    return make_float4(lo.x, lo.y, hi.x, hi.y);
}

template <bool FINAL>
__global__ void gather_layer(const __half* __restrict__ cur, const float* __restrict__ hwk,
                             const int* __restrict__ adj_jj, const int2* __restrict__ adj_proc,
                             const int* __restrict__ off,
                             const float* __restrict__ sc_pre, const float* __restrict__ sc_nxt,
                             const float* __restrict__ Wp, const float* __restrict__ Wn,
                             const float* __restrict__ Wng, const float* __restrict__ Wsf,
                             const float* __restrict__ bp, const float* __restrict__ bn,
                             const float* __restrict__ bsg,
                             __half* __restrict__ out, float* __restrict__ scores) {
    __shared__ float WpS[256], WnS[256], WngS[256], WsfS[256], bs[16];
    int t = threadIdx.x;
    WpS[t] = Wp[t]; WnS[t] = Wn[t]; WngS[t] = Wng[t]; WsfS[t] = Wsf[t];
    if (t < 16) bs[t] = bp[t] + bn[t] + bsg[t];
    __syncthreads();
    unsigned gid = blockIdx.x * 256 + t;
    unsigned v = gid >> 2, c = gid & 3;
    if (v >= N_JOB) return;
    const int* rend0 = off;
    const int* rend1 = off + N_JOB;
    const int* rend2 = off + 2 * N_JOB;
    int e0 = rend0[v], s0 = v ? rend0[v - 1] : 0;
    int e1 = rend1[v], s1 = v ? rend1[v - 1] : E_PRE;
    int e2 = rend2[v], s2 = v ? rend2[v - 1] : 0;

    float4 accP = make_float4(0.f, 0.f, 0.f, 0.f);
    {
        int p = s0;
        for (; p + 1 < e0; p += 2) {
            int sa = adj_jj[p], sb = adj_jj[p + 1];
            float wa = sc_pre[sa], wb = sc_pre[sb];
            float4 ha = load_h16(cur, sa, c);
            float4 hb = load_h16(cur, sb, c);
            accP.x += ha.x * wa + hb.x * wb; accP.y += ha.y * wa + hb.y * wb;
            accP.z += ha.z * wa + hb.z * wb; accP.w += ha.w * wa + hb.w * wb;
        }
        if (p < e0) {
            int sa = adj_jj[p];
            float wa = sc_pre[sa];
            float4 ha = load_h16(cur, sa, c);
            accP.x += ha.x * wa; accP.y += ha.y * wa; accP.z += ha.z * wa; accP.w += ha.w * wa;
        }
    }
    float4 accN = make_float4(0.f, 0.f, 0.f, 0.f);
    {
        int p = s1;
        for (; p + 1 < e1; p += 2) {
            int sa = adj_jj[p], sb = adj_jj[p + 1];
            float wa = sc_nxt[sa], wb = sc_nxt[sb];
            float4 ha = load_h16(cur, sa, c);
            float4 hb = load_h16(cur, sb, c);
            accN.x += ha.x * wa + hb.x * wb; accN.y += ha.y * wa + hb.y * wb;
            accN.z += ha.z * wa + hb.z * wb; accN.w += ha.w * wa + hb.w * wb;
        }
        if (p < e1) {
            int sa = adj_jj[p];
            float wa = sc_nxt[sa];
            float4 ha = load_h16(cur, sa, c);
            accN.x += ha.x * wa; accN.y += ha.y * wa; accN.z += ha.z * wa; accN.w += ha.w * wa;
        }
    }
    float4 accS = make_float4(0.f, 0.f, 0.f, 0.f);
    for (int p = s2; p < e2; ++p) {
        int sa = adj_proc[p].x;
        float4 ha = ((const float4*)(hwk + (size_t)sa * 16))[c];
        accS.x += ha.x; accS.y += ha.y; accS.z += ha.z; accS.w += ha.w;
    }

    int d0 = e0 - s0, d1 = e1 - s1, d2 = e2 - s2;
    float rp = rsqrtf((float)(d0 < 1 ? 1 : d0));
    float rn = rsqrtf((float)(d1 < 1 ? 1 : d1));
    float ri = 1.0f / (float)(d2 < 1 ? 1 : d2);
    accP.x *= rp; accP.y *= rp; accP.z *= rp; accP.w *= rp;
    accN.x *= rn; accN.y *= rn; accN.z *= rn; accN.w *= rn;
    accS.x *= ri; accS.y *= ri; accS.z *= ri; accS.w *= ri;

    float o[4];
#pragma unroll
    for (int j = 0; j < 4; ++j) o[j] = bs[c * 4 + j];
    mm_accum(WpS, accP, c, o);
    mm_accum(WnS, accN, c, o);
    mm_accum(WngS, accS, c, o);
    float4 hself = load_h16(cur, v, c);
    mm_accum(WsfS, hself, c, o);

    if (!FINAL) {
        uint2* dst = (uint2*)(out + (size_t)v * 16 + c * 4);
        *dst = make_uint2(pack_h2(o[0], o[1]), pack_h2(o[2], o[3]));
    } else {
        for (int p = s2; p < e2; ++p) {
            int2 pr = adj_proc[p];
            float4 wv = ((const float4*)(hwk + (size_t)pr.x * 16))[c];
            float d = o[0] * wv.x + o[1] * wv.y + o[2] * wv.z + o[3] * wv.w;
            d += __shfl_xor(d, 1, 4);
            d += __shfl_xor(d, 2, 4);
            if (c == 0) scores[pr.y] = d;
        }
    }
}

extern "C" void kernel_launch(void* const* d_in, const int* in_sizes, int n_in,
                              void* d_out, int out_size, void* d_ws, size_t ws_size,
                              hipStream_t stream) {
    const float* job_feat     = (const float*)d_in[0];
    const float* worker_feat  = (const float*)d_in[1];
    const int*   pre_src      = (const int*)d_in[2];
    const int*   pre_dst      = (const int*)d_in[3];
    const int*   nxt_src      = (const int*)d_in[4];
    const int*   nxt_dst      = (const int*)d_in[5];
    const int*   proc_src     = (const int*)d_in[6];
    const int*   proc_dst     = (const int*)d_in[7];
    const float* W_emb_job    = (const float*)d_in[8];
    const float* b_emb_job    = (const float*)d_in[9];
    const float* W_emb_worker = (const float*)d_in[10];
    const float* b_emb_worker = (const float*)d_in[11];
    const float* W_pre        = (const float*)d_in[12];
    const float* b_pre        = (const float*)d_in[13];
    const float* W_nxt        = (const float*)d_in[14];
    const float* b_nxt        = (const float*)d_in[15];
    const float* W_self       = (const float*)d_in[16];
    const float* W_neigh      = (const float*)d_in[17];
    const float* b_sage       = (const float*)d_in[18];
    float* out = (float*)d_out;

    // Workspace (~125 MB). fp16 h buffers + hw alias the dead bucket region.
    float* ws = (float*)d_ws;
    __half* h16A = (__half*)ws;                         // 8M halfs = 4M u32
    __half* h16B = (__half*)(ws + 4000000);             // 8M halfs = 4M u32
    float*  hw   = ws + 8000000;                        //   800,000 f
    unsigned* jjb = (unsigned*)ws;                      // 124*67584 = 8,380,416 u32
    int2*  procb  = (int2*)(ws + 8380416);              // 62*34000 int2
    unsigned short* srcb = (unsigned short*)(ws + 12596416); // 124*67584 u16
    int*   off  = (int*)(ws + 16800000);                // 1,500,000 (row ends)
    int*   gcur = off + 3 * N_JOB;                      // 512
    int*   adj_jj = gcur + 512;                         // 8,000,000
    int2*  adj_proc = (int2*)(adj_jj + 8000000);        // 2,000,000 int2
    float* sc_pre = (float*)(adj_proc + 2000000);       // 500,000
    float* sc_nxt = sc_pre + N_JOB;                     // 500,000

    cursor_init<<<1, 512, 0, stream>>>(gcur);
    partition_kernel<<<2 * NB_PRE + NB_PROC, 256, 0, stream>>>(
        pre_src, pre_dst, nxt_src, nxt_dst, proc_src, proc_dst,
        gcur, jjb, procb, srcb);
    csr_build<<<3 * NWIN, 256, 0, stream>>>(jjb, procb, gcur, off, adj_jj, adj_proc);
    outdeg_build<<<2 * NWIN, 256, 0, stream>>>(srcb, gcur, sc_pre, sc_nxt);

    embed_kernel<7, true><<<(N_JOB + 255) / 256, 256, 0, stream>>>(
        job_feat, W_emb_job, b_emb_job, h16A, N_JOB);
    embed_kernel<3, false><<<(N_WORKER + 255) / 256, 256, 0, stream>>>(
        worker_feat, W_emb_worker, b_emb_worker, hw, N_WORKER);

    const int GGRID = (4 * N_JOB + 255) / 256;
    gather_layer<false><<<GGRID, 256, 0, stream>>>(
        h16A, hw, adj_jj, adj_proc, off, sc_pre, sc_nxt,
        W_pre, W_nxt, W_neigh, W_self, b_pre, b_nxt, b_sage, h16B, nullptr);
    gather_layer<true><<<GGRID, 256, 0, stream>>>(
        h16B, hw, adj_jj, adj_proc, off, sc_pre, sc_nxt,
        W_pre, W_nxt, W_neigh, W_self, b_pre, b_nxt, b_sage, nullptr, out);
}

// Round 10
// 914.105 us; speedup vs baseline: 1.5378x; 1.5378x over previous
//
#include <hip/hip_runtime.h>
#include <hip/hip_fp16.h>

#define N_JOB 500000
#define N_WORKER 50000
#define E_PRE 4000000
#define E_NXT 4000000
#define E_PROC 2000000

// dst windows: 62 x 8192 nodes. src groups: 16 x 32768 nodes (1MB fp16 h).
#define WBITS 13
#define WSZ 8192
#define NWIN 62
#define GBITS 15
#define NGRP 16
#define SEGW (NWIN * NGRP)          // 992 (dst-window, src-group) cells per rel
#define CAP_JJ 4864                 // cell mean 4295 + ~8.7 sigma (65.5)
#define CAP_PR 34000                // window mean 32768 + 6.8 sigma
#define CAP_SR 67584                // window mean 65536 + 8 sigma

#define GCUR_PROC (2 * SEGW)        // 1984
#define GCUR_SRC (GCUR_PROC + NWIN) // 2046
#define NSEG_TOT (GCUR_SRC + 2 * NWIN) // 2170

#define EPB 16384
#define NB_PRE ((E_PRE + EPB - 1) / EPB)    // 245
#define NB_PROC ((E_PROC + EPB - 1) / EPB)  // 123

__global__ void cursor_init(int* __restrict__ gcur) {
    for (int k = threadIdx.x; k < NSEG_TOT; k += 1024) {
        if (k < GCUR_PROC)      gcur[k] = k * CAP_JJ;
        else if (k < GCUR_SRC)  gcur[k] = (k - GCUR_PROC) * CAP_PR;
        else                    gcur[k] = (k - GCUR_SRC) * CAP_SR;
    }
}

// ---------------------------------------------------------------------------
// Partition: each block owns 16384 edges of one relation. jj edges are
// LDS-histogrammed by (dst_window, src_group) -> 992-cell reservation ->
// replay with plain stores. Also emits u16 src-locals for outdeg.
// jj entry: (dst&8191)<<19|src. proc: ((dl<<16)|src, eid).
// ---------------------------------------------------------------------------
__global__ __launch_bounds__(256) void partition_kernel(
        const int* __restrict__ pre_src, const int* __restrict__ pre_dst,
        const int* __restrict__ nxt_src, const int* __restrict__ nxt_dst,
        const int* __restrict__ proc_src, const int* __restrict__ proc_dst,
        int* __restrict__ gcur, unsigned* __restrict__ jjb,
        int2* __restrict__ procb, unsigned short* __restrict__ srcb) {
    __shared__ int cntD[SEGW], basD[SEGW], curD[SEGW];
    __shared__ int cntS[NWIN], basS[NWIN], curS[NWIN];
    int t = threadIdx.x;
    int b = blockIdx.x;
    int rel, lo, hi;
    const int *dstp, *srcp;
    if (b < NB_PRE) {
        rel = 0; dstp = pre_dst; srcp = pre_src;
        lo = b * EPB; hi = min(lo + EPB, E_PRE);
    } else if (b < 2 * NB_PRE) {
        rel = 1; b -= NB_PRE; dstp = nxt_dst; srcp = nxt_src;
        lo = b * EPB; hi = min(lo + EPB, E_NXT);
    } else {
        rel = 2; b -= 2 * NB_PRE; dstp = proc_dst; srcp = proc_src;
        lo = b * EPB; hi = min(lo + EPB, E_PROC);
    }
    if (rel < 2) {
        for (int k = t; k < SEGW; k += 256) cntD[k] = 0;
        for (int k = t; k < NWIN; k += 256) cntS[k] = 0;
        __syncthreads();
        for (int i = lo + t; i < hi; i += 256) {
            int d = dstp[i], s = srcp[i];
            atomicAdd(&cntD[((d >> WBITS) << 4) | (s >> GBITS)], 1);
            atomicAdd(&cntS[s >> WBITS], 1);
        }
        __syncthreads();
        for (int k = t; k < SEGW; k += 256) {
            int c = cntD[k];
            basD[k] = c ? atomicAdd(&gcur[rel * SEGW + k], c) : 0;
            curD[k] = 0;
        }
        for (int k = t; k < NWIN; k += 256) {
            int c = cntS[k];
            basS[k] = c ? atomicAdd(&gcur[GCUR_SRC + rel * NWIN + k], c) : 0;
            curS[k] = 0;
        }
        __syncthreads();
        for (int i = lo + t; i < hi; i += 256) {
            int d = dstp[i], s = srcp[i];
            int seg = ((d >> WBITS) << 4) | (s >> GBITS);
            int pD = basD[seg] + atomicAdd(&curD[seg], 1);
            jjb[pD] = ((unsigned)(d & (WSZ - 1)) << 19) | (unsigned)s;
            int sw = s >> WBITS;
            int pS = basS[sw] + atomicAdd(&curS[sw], 1);
            srcb[pS] = (unsigned short)(s & (WSZ - 1));
        }
    } else {
        for (int k = t; k < NWIN; k += 256) cntD[k] = 0;
        __syncthreads();
        for (int i = lo + t; i < hi; i += 256)
            atomicAdd(&cntD[dstp[i] >> WBITS], 1);
        __syncthreads();
        for (int k = t; k < NWIN; k += 256) {
            int c = cntD[k];
            basD[k] = c ? atomicAdd(&gcur[GCUR_PROC + k], c) : 0;
            curD[k] = 0;
        }
        __syncthreads();
        for (int i = lo + t; i < hi; i += 256) {
            int d = dstp[i], s = srcp[i];
            int wd = d >> WBITS;
            int pD = basD[wd] + atomicAdd(&curD[wd], 1);
            procb[pD] = make_int2(((d & (WSZ - 1)) << 16) | s, i);
        }
    }
}

// ---------------------------------------------------------------------------
// csr_build: one block per (rel,window). hist over the window's 16 src-group
// sub-segments -> LDS scan -> row ENDS -> scatter sub-segments in group order
// (single read; 15 barriers) so each CSR row is src-group sorted.
// ---------------------------------------------------------------------------
__global__ __launch_bounds__(256) void csr_build(
        const unsigned* __restrict__ jjb, const int2* __restrict__ procb,
        const int* __restrict__ gcur, int* __restrict__ off,
        int* __restrict__ adj_jj, int2* __restrict__ adj_proc) {
    __shared__ int hist[WSZ];
    __shared__ int scanB[WSZ];
    __shared__ int part[256];
    __shared__ int wcnt[NWIN];
    __shared__ int baseS;
    int t = threadIdx.x;
    int rel = blockIdx.x / NWIN;
    int w = blockIdx.x % NWIN;
    if (rel < 2) {
        for (int i = t; i < NWIN; i += 256) {
            int s = 0;
            for (int g = 0; g < NGRP; ++g) {
                int idx = rel * SEGW + i * NGRP + g;
                s += gcur[idx] - idx * CAP_JJ;
            }
            wcnt[i] = s;
        }
    } else {
        for (int i = t; i < NWIN; i += 256)
            wcnt[i] = gcur[GCUR_PROC + i] - i * CAP_PR;
    }
    for (int i = t; i < WSZ; i += 256) hist[i] = 0;
    __syncthreads();
    if (t == 0) {
        int bb = (rel == 1) ? E_PRE : 0;
        for (int i = 0; i < w; ++i) bb += wcnt[i];
        baseS = bb;
    }
    if (rel < 2) {
        for (int g = 0; g < NGRP; ++g) {
            int idx = rel * SEGW + w * NGRP + g;
            int sb = idx * CAP_JJ, se = gcur[idx];
            for (int p = sb + t; p < se; p += 256)
                atomicAdd(&hist[jjb[p] >> 19], 1);
        }
    } else {
        int sb = w * CAP_PR, se = gcur[GCUR_PROC + w];
        for (int p = sb + t; p < se; p += 256)
            atomicAdd(&hist[procb[p].x >> 16], 1);
    }
    __syncthreads();
    {
        int mb = t * 32;
        int sum = 0;
        for (int j = 0; j < 32; ++j) { int v = hist[mb + j]; scanB[mb + j] = sum; sum += v; }
        part[t] = sum;
        __syncthreads();
        if (t == 0) { int r = 0; for (int i = 0; i < 256; ++i) { int v = part[i]; part[i] = r; r += v; } }
        __syncthreads();
        int add = part[t] + baseS;
        for (int j = 0; j < 32; ++j) scanB[mb + j] += add;
    }
    __syncthreads();
    int nlo = w * WSZ;
    int nloc = min(WSZ, N_JOB - nlo);
    for (int i = t; i < nloc; i += 256)
        off[rel * N_JOB + nlo + i] = scanB[i] + hist[i];   // row ENDS
    __syncthreads();
    if (rel < 2) {
        for (int g = 0; g < NGRP; ++g) {
            int idx = rel * SEGW + w * NGRP + g;
            int sb = idx * CAP_JJ, se = gcur[idx];
            for (int p = sb + t; p < se; p += 256) {
                unsigned e = jjb[p];
                int slot = atomicAdd(&scanB[e >> 19], 1);
                adj_jj[slot] = (int)(e & 0x7FFFFu);
            }
            __syncthreads();   // keep group order within rows
        }
    } else {
        int sb = w * CAP_PR, se = gcur[GCUR_PROC + w];
        for (int p = sb + t; p < se; p += 256) {
            int2 e = procb[p];
            int slot = atomicAdd(&scanB[e.x >> 16], 1);
            adj_proc[slot] = make_int2(e.x & 0xFFFF, e.y);
        }
    }
}

// ---------------------------------------------------------------------------
// outdeg_build: one block per (rel,window); LDS histogram of u16 src-locals,
// writes rsqrt(max(deg,1)) floats directly.
// ---------------------------------------------------------------------------
__global__ __launch_bounds__(256) void outdeg_build(
        const unsigned short* __restrict__ srcb, const int* __restrict__ gcur,
        float* __restrict__ sc_pre, float* __restrict__ sc_nxt) {
    __shared__ int hist[WSZ];
    int t = threadIdx.x;
    int rel = blockIdx.x / NWIN;
    int w = blockIdx.x % NWIN;
    int k = rel * NWIN + w;
    int segbase = k * CAP_SR;
    int segend = gcur[GCUR_SRC + k];
    for (int i = t; i < WSZ; i += 256) hist[i] = 0;
    __syncthreads();
    int cnt = segend - segbase;
    const unsigned* p2 = (const unsigned*)(srcb + segbase);
    int n2 = cnt >> 1;
    for (int i = t; i < n2; i += 256) {
        unsigned v = p2[i];
        atomicAdd(&hist[v & 0xFFFFu], 1);
        atomicAdd(&hist[v >> 16], 1);
    }
    if (t == 0 && (cnt & 1)) atomicAdd(&hist[srcb[segend - 1]], 1);
    __syncthreads();
    float* scp = rel ? sc_nxt : sc_pre;
    int nlo = w * WSZ;
    int nloc = min(WSZ, N_JOB - nlo);
    for (int i = t; i < nloc; i += 256) {
        int d = hist[i];
        scp[nlo + i] = rsqrtf((float)(d < 1 ? 1 : d));
    }
}

__device__ __forceinline__ unsigned pack_h2(float a, float b) {
    __half2 h = __float22half2_rn(make_float2(a, b));
    return *reinterpret_cast<unsigned*>(&h);
}
__device__ __forceinline__ float2 unpack_h2(unsigned u) {
    __half2 h = *reinterpret_cast<__half2*>(&u);
    return __half22float2(h);
}

// ---------------------------------------------------------------------------
// Embedding. HOUT=true: write fp16 row (16 halfs). HOUT=false: f32 row (hw).
// ---------------------------------------------------------------------------
template <int F, bool HOUT>
__global__ void embed_kernel(const float* __restrict__ feat, const float* __restrict__ W,
                             const float* __restrict__ b, void* __restrict__ outp, int n) {
    __shared__ float Ws[F * 16];
    __shared__ float bs[16];
    int t = threadIdx.x;
    if (t < F * 16) Ws[t] = W[t];
    if (t < 16) bs[t] = b[t];
    __syncthreads();
    int i = blockIdx.x * blockDim.x + t;
    if (i >= n) return;
    float f[F];
#pragma unroll
    for (int k = 0; k < F; k++) f[k] = feat[(size_t)i * F + k];
    float o[16];
#pragma unroll
    for (int d = 0; d < 16; d++) {
        float s = bs[d];
#pragma unroll
        for (int k = 0; k < F; k++) s += f[k] * Ws[k * 16 + d];
        o[d] = s;
    }
    if (HOUT) {
        uint4* dst = (uint4*)((__half*)outp + (size_t)i * 16);
        dst[0] = make_uint4(pack_h2(o[0], o[1]), pack_h2(o[2], o[3]),
                            pack_h2(o[4], o[5]), pack_h2(o[6], o[7]));
        dst[1] = make_uint4(pack_h2(o[8], o[9]), pack_h2(o[10], o[11]),
                            pack_h2(o[12], o[13]), pack_h2(o[14], o[15]));
    } else {
        float4* dst4 = (float4*)((float*)outp + (size_t)i * 16);
        dst4[0] = make_float4(o[0], o[1], o[2], o[3]);
        dst4[1] = make_float4(o[4], o[5], o[6], o[7]);
        dst4[2] = make_float4(o[8], o[9], o[10], o[11]);
        dst4[3] = make_float4(o[12], o[13], o[14], o[15]);
    }
}

// ---------------------------------------------------------------------------
// Merged per-layer gather with fp16 node features; rows src-group sorted so
// concurrent gathers hit a ~1-2MB L2-fitting window. FINAL writes scores only.
// ---------------------------------------------------------------------------
__device__ __forceinline__ void mm_accum(const float* __restrict__ Ws, float4 a, int c, float o[4]) {
#pragma unroll
    for (int g = 0; g < 4; ++g) {
        float a0 = __shfl(a.x, g, 4);
        float a1 = __shfl(a.y, g, 4);
        float a2 = __shfl(a.z, g, 4);
        float a3 = __shfl(a.w, g, 4);
        const float* wr = &Ws[(4 * g) * 16 + c * 4];
#pragma unroll
        for (int j = 0; j < 4; ++j)
            o[j] += a0 * wr[j] + a1 * wr[16 + j] + a2 * wr[32 + j] + a3 * wr[48 + j];
    }
}

__device__ __forceinline__ float4 load_h16(const __half* __restrict__ h16, int row, int c) {
    uint2 raw = *(const uint2*)(h16 + (size_t)row * 16 + c * 4);
    float2 lo = unpack_h2(raw.x), hi = unpack_h2(raw.y);
    return make_float4(lo.x, lo.y, hi.x, hi.y);
}

template <bool FINAL>
__global__ void gather_layer(const __half* __restrict__ cur, const float* __restrict__ hwk,
                             const int* __restrict__ adj_jj, const int2* __restrict__ adj_proc,
                             const int* __restrict__ off,
                             const float* __restrict__ sc_pre, const float* __restrict__ sc_nxt,
                             const float* __restrict__ Wp, const float* __restrict__ Wn,
                             const float* __restrict__ Wng, const float* __restrict__ Wsf,
                             const float* __restrict__ bp, const float* __restrict__ bn,
                             const float* __restrict__ bsg,
                             __half* __restrict__ out, float* __restrict__ scores) {
    __shared__ float WpS[256], WnS[256], WngS[256], WsfS[256], bs[16];
    int t = threadIdx.x;
    WpS[t] = Wp[t]; WnS[t] = Wn[t]; WngS[t] = Wng[t]; WsfS[t] = Wsf[t];
    if (t < 16) bs[t] = bp[t] + bn[t] + bsg[t];
    __syncthreads();
    unsigned gid = blockIdx.x * 256 + t;
    unsigned v = gid >> 2, c = gid & 3;
    if (v >= N_JOB) return;
    const int* rend0 = off;
    const int* rend1 = off + N_JOB;
    const int* rend2 = off + 2 * N_JOB;
    int e0 = rend0[v], s0 = v ? rend0[v - 1] : 0;
    int e1 = rend1[v], s1 = v ? rend1[v - 1] : E_PRE;
    int e2 = rend2[v], s2 = v ? rend2[v - 1] : 0;

    float4 accP = make_float4(0.f, 0.f, 0.f, 0.f);
    {
        int p = s0;
        for (; p + 1 < e0; p += 2) {
            int sa = adj_jj[p], sb = adj_jj[p + 1];
            float wa = sc_pre[sa], wb = sc_pre[sb];
            float4 ha = load_h16(cur, sa, c);
            float4 hb = load_h16(cur, sb, c);
            accP.x += ha.x * wa + hb.x * wb; accP.y += ha.y * wa + hb.y * wb;
            accP.z += ha.z * wa + hb.z * wb; accP.w += ha.w * wa + hb.w * wb;
        }
        if (p < e0) {
            int sa = adj_jj[p];
            float wa = sc_pre[sa];
            float4 ha = load_h16(cur, sa, c);
            accP.x += ha.x * wa; accP.y += ha.y * wa; accP.z += ha.z * wa; accP.w += ha.w * wa;
        }
    }
    float4 accN = make_float4(0.f, 0.f, 0.f, 0.f);
    {
        int p = s1;
        for (; p + 1 < e1; p += 2) {
            int sa = adj_jj[p], sb = adj_jj[p + 1];
            float wa = sc_nxt[sa], wb = sc_nxt[sb];
            float4 ha = load_h16(cur, sa, c);
            float4 hb = load_h16(cur, sb, c);
            accN.x += ha.x * wa + hb.x * wb; accN.y += ha.y * wa + hb.y * wb;
            accN.z += ha.z * wa + hb.z * wb; accN.w += ha.w * wa + hb.w * wb;
        }
        if (p < e1) {
            int sa = adj_jj[p];
            float wa = sc_nxt[sa];
            float4 ha = load_h16(cur, sa, c);
            accN.x += ha.x * wa; accN.y += ha.y * wa; accN.z += ha.z * wa; accN.w += ha.w * wa;
        }
    }
    float4 accS = make_float4(0.f, 0.f, 0.f, 0.f);
    for (int p = s2; p < e2; ++p) {
        int sa = adj_proc[p].x;
        float4 ha = ((const float4*)(hwk + (size_t)sa * 16))[c];
        accS.x += ha.x; accS.y += ha.y; accS.z += ha.z; accS.w += ha.w;
    }

    int d0 = e0 - s0, d1 = e1 - s1, d2 = e2 - s2;
    float rp = rsqrtf((float)(d0 < 1 ? 1 : d0));
    float rn = rsqrtf((float)(d1 < 1 ? 1 : d1));
    float ri = 1.0f / (float)(d2 < 1 ? 1 : d2);
    accP.x *= rp; accP.y *= rp; accP.z *= rp; accP.w *= rp;
    accN.x *= rn; accN.y *= rn; accN.z *= rn; accN.w *= rn;
    accS.x *= ri; accS.y *= ri; accS.z *= ri; accS.w *= ri;

    float o[4];
#pragma unroll
    for (int j = 0; j < 4; ++j) o[j] = bs[c * 4 + j];
    mm_accum(WpS, accP, c, o);
    mm_accum(WnS, accN, c, o);
    mm_accum(WngS, accS, c, o);
    float4 hself = load_h16(cur, v, c);
    mm_accum(WsfS, hself, c, o);

    if (!FINAL) {
        uint2* dst = (uint2*)(out + (size_t)v * 16 + c * 4);
        *dst = make_uint2(pack_h2(o[0], o[1]), pack_h2(o[2], o[3]));
    } else {
        for (int p = s2; p < e2; ++p) {
            int2 pr = adj_proc[p];
            float4 wv = ((const float4*)(hwk + (size_t)pr.x * 16))[c];
            float d = o[0] * wv.x + o[1] * wv.y + o[2] * wv.z + o[3] * wv.w;
            d += __shfl_xor(d, 1, 4);
            d += __shfl_xor(d, 2, 4);
            if (c == 0) scores[pr.y] = d;
        }
    }
}

extern "C" void kernel_launch(void* const* d_in, const int* in_sizes, int n_in,
                              void* d_out, int out_size, void* d_ws, size_t ws_size,
                              hipStream_t stream) {
    const float* job_feat     = (const float*)d_in[0];
    const float* worker_feat  = (const float*)d_in[1];
    const int*   pre_src      = (const int*)d_in[2];
    const int*   pre_dst      = (const int*)d_in[3];
    const int*   nxt_src      = (const int*)d_in[4];
    const int*   nxt_dst      = (const int*)d_in[5];
    const int*   proc_src     = (const int*)d_in[6];
    const int*   proc_dst     = (const int*)d_in[7];
    const float* W_emb_job    = (const float*)d_in[8];
    const float* b_emb_job    = (const float*)d_in[9];
    const float* W_emb_worker = (const float*)d_in[10];
    const float* b_emb_worker = (const float*)d_in[11];
    const float* W_pre        = (const float*)d_in[12];
    const float* b_pre        = (const float*)d_in[13];
    const float* W_nxt        = (const float*)d_in[14];
    const float* b_nxt        = (const float*)d_in[15];
    const float* W_self       = (const float*)d_in[16];
    const float* W_neigh      = (const float*)d_in[17];
    const float* b_sage       = (const float*)d_in[18];
    float* out = (float*)d_out;

    // Workspace (~114 MB, u32 offsets). Buckets alias h buffers (disjoint in
    // time); adj_proc aliases srcb (dead after outdeg_build).
    float* ws = (float*)d_ws;
    __half* h16A = (__half*)ws;                              // [0, 4M)
    __half* h16B = (__half*)(ws + 4000000);                  // [4M, 8M)
    float*  hw   = ws + 8000000;                             // [8M, 8.8M)
    unsigned* jjb = (unsigned*)ws;                           // [0, 9,650,176)
    int2*  procb  = (int2*)(ws + 9650176);                   // [9.65M, 13,866,176)
    unsigned short* srcb = (unsigned short*)(ws + 13866176); // [13.87M, 18,056,384)
    int2*  adj_proc = (int2*)(ws + 13866176);                // aliases srcb (4M u32)
    int*   off  = (int*)(ws + 18056384);                     // 1,500,000
    int*   gcur = off + 3 * N_JOB;                           // 2,560 pad
    int*   adj_jj = gcur + 2560;                             // 8,000,000
    float* sc_pre = (float*)(adj_jj + 8000000);              // 500,000
    float* sc_nxt = sc_pre + N_JOB;                          // 500,000

    cursor_init<<<1, 1024, 0, stream>>>(gcur);
    partition_kernel<<<2 * NB_PRE + NB_PROC, 256, 0, stream>>>(
        pre_src, pre_dst, nxt_src, nxt_dst, proc_src, proc_dst,
        gcur, jjb, procb, srcb);
    outdeg_build<<<2 * NWIN, 256, 0, stream>>>(srcb, gcur, sc_pre, sc_nxt);
    csr_build<<<3 * NWIN, 256, 0, stream>>>(jjb, procb, gcur, off, adj_jj, adj_proc);

    embed_kernel<7, true><<<(N_JOB + 255) / 256, 256, 0, stream>>>(
        job_feat, W_emb_job, b_emb_job, h16A, N_JOB);
    embed_kernel<3, false><<<(N_WORKER + 255) / 256, 256, 0, stream>>>(
        worker_feat, W_emb_worker, b_emb_worker, hw, N_WORKER);

    const int GGRID = (4 * N_JOB + 255) / 256;
    gather_layer<false><<<GGRID, 256, 0, stream>>>(
        h16A, hw, adj_jj, adj_proc, off, sc_pre, sc_nxt,
        W_pre, W_nxt, W_neigh, W_self, b_pre, b_nxt, b_sage, h16B, nullptr);
    gather_layer<true><<<GGRID, 256, 0, stream>>>(
        h16B, hw, adj_jj, adj_proc, off, sc_pre, sc_nxt,
        W_pre, W_nxt, W_neigh, W_self, b_pre, b_nxt, b_sage, nullptr, out);
}